// Round 7
// baseline (2275.525 us; speedup 1.0000x reference)
//
#include <hip/hip_runtime.h>

#define NN 100000      // nodes
#define NE 1000000     // edges per relation
#define RR 4           // relations
#define GG 256         // graphs
#define DHID 128       // feature width (DIN == DH == 128)
#define NCLS 10        // classes
#define RN (RR * NN)   // virtual segments (r, dst)
#define NBLK ((RN + 1023) / 1024)
#define HBW 64         // packed bf16 row width in uints (128 bf16)
#define NTILE ((NN + 63) / 64)   // 1563 dst tiles

// ---- bf16 helpers (packed 2 per uint; low ushort = even col) ----
__device__ __forceinline__ float bflo(unsigned v) { return __int_as_float((int)(v << 16)); }
__device__ __forceinline__ float bfhi(unsigned v) { return __int_as_float((int)(v & 0xffff0000u)); }
__device__ __forceinline__ unsigned pack_bf2(float a, float b) {
    unsigned ua = __float_as_uint(a), ub = __float_as_uint(b);
    ua = (ua + 0x7fffu + ((ua >> 16) & 1u)) >> 16;     // round-to-nearest-even
    ub = (ub + 0x7fffu + ((ub >> 16) & 1u)) >> 16;
    return ua | (ub << 16);
}

// ---------------------------------------------------------------- degrees ---
__global__ __launch_bounds__(256) void degree_count(const int* __restrict__ edges,
                                                    int* __restrict__ cnt_out,
                                                    int* __restrict__ cnt_in) {
    int t = blockIdx.x * 256 + threadIdx.x;
    if (t >= RR * NE) return;
    int r = t / NE;
    int e = t - r * NE;
    const int* base = edges + (size_t)r * 2 * NE;
    atomicAdd(&cnt_out[r * NN + base[e]], 1);
    atomicAdd(&cnt_in[r * NN + base[NE + e]], 1);
}

__global__ __launch_bounds__(256) void deg_to_scale(const int* __restrict__ cnt_out,
                                                    const int* __restrict__ cnt_in,
                                                    float* __restrict__ so,
                                                    float* __restrict__ si) {
    int t = blockIdx.x * 256 + threadIdx.x;
    if (t >= RN) return;
    int co = cnt_out[t], ci = cnt_in[t];
    so[t] = rsqrtf((float)(co < 1 ? 1 : co));
    si[t] = rsqrtf((float)(ci < 1 ? 1 : ci));
}

// ------------------------------------------------------------- CSR build ----
__global__ __launch_bounds__(256) void scan_partial(const int* __restrict__ cnt,
                                                    int* __restrict__ partial) {
    __shared__ int sdat[256];
    int t = threadIdx.x;
    int base = blockIdx.x * 1024 + t * 4;
    int s = 0;
    #pragma unroll
    for (int i = 0; i < 4; ++i)
        if (base + i < RN) s += cnt[base + i];
    sdat[t] = s;
    __syncthreads();
    for (int off = 128; off > 0; off >>= 1) {
        if (t < off) sdat[t] += sdat[t + off];
        __syncthreads();
    }
    if (t == 0) partial[blockIdx.x] = sdat[0];
}

__global__ __launch_bounds__(512) void scan_block(int* __restrict__ partial) {
    __shared__ int s[512];
    int t = threadIdx.x;
    s[t] = (t < NBLK) ? partial[t] : 0;
    __syncthreads();
    for (int off = 1; off < 512; off <<= 1) {
        int v = (t >= off) ? s[t - off] : 0;
        __syncthreads();
        s[t] += v;
        __syncthreads();
    }
    if (t < NBLK) partial[t] = (t == 0) ? 0 : s[t - 1];
}

__global__ __launch_bounds__(256) void scan_write(const int* __restrict__ cnt,
                                                  const int* __restrict__ partial,
                                                  int* __restrict__ row_ptr,
                                                  int* __restrict__ cursor) {
    __shared__ int ssum[256];
    int t = threadIdx.x;
    int base = blockIdx.x * 1024 + t * 4;
    int c[4];
    #pragma unroll
    for (int i = 0; i < 4; ++i)
        c[i] = (base + i < RN) ? cnt[base + i] : 0;
    ssum[t] = c[0] + c[1] + c[2] + c[3];
    __syncthreads();
    for (int off = 1; off < 256; off <<= 1) {
        int v = (t >= off) ? ssum[t - off] : 0;
        __syncthreads();
        ssum[t] += v;
        __syncthreads();
    }
    int e = partial[blockIdx.x] + (t == 0 ? 0 : ssum[t - 1]);
    #pragma unroll
    for (int i = 0; i < 4; ++i) {
        if (base + i < RN) { row_ptr[base + i] = e; cursor[base + i] = e; e += c[i]; }
    }
    if (blockIdx.x == 0 && t == 0) row_ptr[RN] = RR * NE;
}

// packed edge record: .x = src index, .y = float bits of so[src]*si[dst]
__global__ __launch_bounds__(256) void fill_csr(const int* __restrict__ edges,
                                                const float* __restrict__ so,
                                                const float* __restrict__ si,
                                                int* __restrict__ cursor,
                                                int2* __restrict__ ew) {
    int t = blockIdx.x * 256 + threadIdx.x;
    if (t >= RR * NE) return;
    int r = t / NE;
    int e = t - r * NE;
    const int* eb = edges + (size_t)r * 2 * NE;
    int s = eb[e];
    int d = eb[NE + e];
    int rb = r * NN;
    float w = so[rb + s] * si[rb + d];
    int pos = atomicAdd(&cursor[rb + d], 1);
    ew[pos] = make_int2(s, __float_as_int(w));
}

// ------------------------------------------------------------- tile sort ----
// Rank 1563 dst-tiles by total edge count (desc) so heavy tiles launch first.
// Single block, 2048-slot bitonic in LDS. pack = (weight<<11) | tile.
__global__ __launch_bounds__(1024) void tile_sort(const int* __restrict__ rp,
                                                  int* __restrict__ order) {
    __shared__ int s[2048];
    int t = threadIdx.x;
    for (int i = t; i < 2048; i += 1024) {
        int pk = (int)0x80000000;             // pads sort first (ascending)
        if (i < NTILE) {
            int lo = i * 64;
            int hi = lo + 64; if (hi > NN) hi = NN;
            int w = 0;
            #pragma unroll
            for (int r = 0; r < RR; ++r)
                w += rp[r * NN + hi] - rp[r * NN + lo];
            if (w > (1 << 19)) w = 1 << 19;
            pk = (w << 11) | i;
        }
        s[i] = pk;
    }
    __syncthreads();
    for (int k = 2; k <= 2048; k <<= 1) {
        for (int j = k >> 1; j > 0; j >>= 1) {
            for (int idx = t; idx < 2048; idx += 1024) {
                int pr = idx ^ j;
                if (pr > idx) {
                    int a = s[idx], b = s[pr];
                    bool dir = ((idx & k) == 0);      // ascending network
                    if ((a > b) == dir) { s[idx] = b; s[pr] = a; }
                }
            }
            __syncthreads();
        }
    }
    for (int i = t; i < NTILE; i += 1024)
        order[i] = s[2047 - i] & 0x7FF;               // heaviest first
}

// ------------------------------------------------------------- f32 -> bf16 --
__global__ __launch_bounds__(256) void f32_to_bf16(const float* __restrict__ in,
                                                   unsigned* __restrict__ out) {
    int t = blockIdx.x * 256 + threadIdx.x;
    if (t >= NN * DHID / 4) return;
    float4 v = ((const float4*)in)[t];
    uint2 o;
    o.x = pack_bf2(v.x, v.y);
    o.y = pack_bf2(v.z, v.w);
    ((uint2*)out)[t] = o;
}

// ------------------------------------------------------------- layer --------
// One kernel = one full HeteroGraphConv layer + bias + ReLU (bf16 h storage).
// 64-row tile (via sorted order), As in LDS as bf16. Gather: PAIR scheme —
// lanes 0-31 = edge A, lanes 32-63 = edge B, uint2 (8B) per lane; scalar
// (SGPR) edge records; cross-half sum via shfl_xor(32). GEMM: 4 rows x 8 cols
// per thread. Epilogue: +sum_r b, ReLU, pack bf16, uint4 store.
__global__ __launch_bounds__(256, 4) void layer_kernel(
    const unsigned* __restrict__ hb, const int* __restrict__ row_ptr,
    const int2* __restrict__ ew, const int* __restrict__ order,
    const float* __restrict__ W, const float* __restrict__ b,
    unsigned* __restrict__ hbout) {
    __shared__ unsigned short As[64 * 132];   // bf16 tile, row stride 132
    const int tid  = threadIdx.x;
    const int wave = tid >> 6;
    const int lane = tid & 63;
    const int half = lane >> 5;               // 0: edge A, 1: edge B
    const int lh   = lane & 31;               // covers uints 2lh, 2lh+1
    const int rowbase = order[blockIdx.x] * 64;

    const int rt = tid & 15;          // row thread: owns rows rt+16m
    const int ct = tid >> 4;          // col thread: owns cols ct*8..ct*8+7

    float acc[4][8];
    #pragma unroll
    for (int m = 0; m < 4; ++m)
        #pragma unroll
        for (int i = 0; i < 8; ++i) acc[m][i] = 0.f;

    for (int r = 0; r < RR; ++r) {
        const int rbase = r * NN;
        if (r) __syncthreads();       // previous GEMM done reading As

        // ---- gather: wave owns 16 rows; pair scheme, scalar edge stream ----
        for (int rr = 0; rr < 16; ++rr) {
            int rowLocal = wave * 16 + rr;
            int d = rowbase + rowLocal;
            float a0 = 0.f, a1 = 0.f, a2 = 0.f, a3 = 0.f;
            int j = 0, end = 0;
            if (d < NN) {
                j   = __builtin_amdgcn_readfirstlane(row_ptr[rbase + d]);
                end = __builtin_amdgcn_readfirstlane(row_ptr[rbase + d + 1]);
            }
            // 4 pairs (8 edges) per iter
            for (; j + 8 <= end; j += 8) {
                int2 q0 = ew[j],     q1 = ew[j + 1], q2 = ew[j + 2], q3 = ew[j + 3];
                int2 q4 = ew[j + 4], q5 = ew[j + 5], q6 = ew[j + 6], q7 = ew[j + 7];
                int s0 = half ? q1.x : q0.x;  int b0 = half ? q1.y : q0.y;
                int s1 = half ? q3.x : q2.x;  int b1 = half ? q3.y : q2.y;
                int s2 = half ? q5.x : q4.x;  int b2 = half ? q5.y : q4.y;
                int s3 = half ? q7.x : q6.x;  int b3 = half ? q7.y : q6.y;
                uint2 u0 = *(const uint2*)&hb[(size_t)s0 * HBW + 2 * lh];
                uint2 u1 = *(const uint2*)&hb[(size_t)s1 * HBW + 2 * lh];
                uint2 u2 = *(const uint2*)&hb[(size_t)s2 * HBW + 2 * lh];
                uint2 u3 = *(const uint2*)&hb[(size_t)s3 * HBW + 2 * lh];
                float w0 = __int_as_float(b0), w1 = __int_as_float(b1);
                float w2 = __int_as_float(b2), w3 = __int_as_float(b3);
                a0 = fmaf(w0, bflo(u0.x), a0); a1 = fmaf(w0, bfhi(u0.x), a1);
                a2 = fmaf(w0, bflo(u0.y), a2); a3 = fmaf(w0, bfhi(u0.y), a3);
                a0 = fmaf(w1, bflo(u1.x), a0); a1 = fmaf(w1, bfhi(u1.x), a1);
                a2 = fmaf(w1, bflo(u1.y), a2); a3 = fmaf(w1, bfhi(u1.y), a3);
                a0 = fmaf(w2, bflo(u2.x), a0); a1 = fmaf(w2, bfhi(u2.x), a1);
                a2 = fmaf(w2, bflo(u2.y), a2); a3 = fmaf(w2, bfhi(u2.y), a3);
                a0 = fmaf(w3, bflo(u3.x), a0); a1 = fmaf(w3, bfhi(u3.x), a1);
                a2 = fmaf(w3, bflo(u3.y), a2); a3 = fmaf(w3, bfhi(u3.y), a3);
            }
            // 1 pair per iter
            for (; j + 2 <= end; j += 2) {
                int2 q0 = ew[j], q1 = ew[j + 1];
                int s0 = half ? q1.x : q0.x;  int b0 = half ? q1.y : q0.y;
                uint2 u0 = *(const uint2*)&hb[(size_t)s0 * HBW + 2 * lh];
                float w0 = __int_as_float(b0);
                a0 = fmaf(w0, bflo(u0.x), a0); a1 = fmaf(w0, bfhi(u0.x), a1);
                a2 = fmaf(w0, bflo(u0.y), a2); a3 = fmaf(w0, bfhi(u0.y), a3);
            }
            // odd tail: half B gets weight 0 (same src, zero contribution)
            if (j < end) {
                int2 q0 = ew[j];
                int s0 = q0.x;
                int b0 = half ? 0 : q0.y;
                uint2 u0 = *(const uint2*)&hb[(size_t)s0 * HBW + 2 * lh];
                float w0 = __int_as_float(b0);
                a0 = fmaf(w0, bflo(u0.x), a0); a1 = fmaf(w0, bfhi(u0.x), a1);
                a2 = fmaf(w0, bflo(u0.y), a2); a3 = fmaf(w0, bfhi(u0.y), a3);
            }
            // cross-half reduction: lane l + lane l+32 hold same columns
            a0 += __shfl_xor(a0, 32);
            a1 += __shfl_xor(a1, 32);
            a2 += __shfl_xor(a2, 32);
            a3 += __shfl_xor(a3, 32);
            if (half == 0) {
                uint2 o;
                o.x = pack_bf2(a0, a1);
                o.y = pack_bf2(a2, a3);
                *(uint2*)&As[rowLocal * 132 + 4 * lh] = o;
            }
        }
        __syncthreads();

        // ---- GEMM: acc[m][*] += As[rt+16m][:] @ W_r[:, ct*8..+7] ----
        const float4* Wv = (const float4*)(W + (size_t)r * DHID * DHID);
        for (int k = 0; k < 128; k += 4) {
            uint2 au[4];
            #pragma unroll
            for (int m = 0; m < 4; ++m)
                au[m] = *(const uint2*)&As[(rt + 16 * m) * 132 + k];
            float a[4][4];
            #pragma unroll
            for (int m = 0; m < 4; ++m) {
                a[m][0] = bflo(au[m].x); a[m][1] = bfhi(au[m].x);
                a[m][2] = bflo(au[m].y); a[m][3] = bfhi(au[m].y);
            }
            #pragma unroll
            for (int kk = 0; kk < 4; ++kk) {
                float4 w0 = Wv[(k + kk) * 32 + ct * 2];
                float4 w1 = Wv[(k + kk) * 32 + ct * 2 + 1];
                #pragma unroll
                for (int m = 0; m < 4; ++m) {
                    float x = a[m][kk];
                    acc[m][0] = fmaf(x, w0.x, acc[m][0]);
                    acc[m][1] = fmaf(x, w0.y, acc[m][1]);
                    acc[m][2] = fmaf(x, w0.z, acc[m][2]);
                    acc[m][3] = fmaf(x, w0.w, acc[m][3]);
                    acc[m][4] = fmaf(x, w1.x, acc[m][4]);
                    acc[m][5] = fmaf(x, w1.y, acc[m][5]);
                    acc[m][6] = fmaf(x, w1.z, acc[m][6]);
                    acc[m][7] = fmaf(x, w1.w, acc[m][7]);
                }
            }
        }
    }

    // ---- epilogue: + sum_r b[r], ReLU, pack bf16, store ----
    float bsum[8];
    #pragma unroll
    for (int i = 0; i < 8; ++i) {
        int col = ct * 8 + i;
        bsum[i] = b[0 * DHID + col] + b[1 * DHID + col] +
                  b[2 * DHID + col] + b[3 * DHID + col];
    }
    #pragma unroll
    for (int m = 0; m < 4; ++m) {
        int row = rowbase + rt + 16 * m;
        if (row < NN) {
            float o[8];
            #pragma unroll
            for (int i = 0; i < 8; ++i)
                o[i] = fmaxf(acc[m][i] + bsum[i], 0.f);
            uint4 pk;
            pk.x = pack_bf2(o[0], o[1]);
            pk.y = pack_bf2(o[2], o[3]);
            pk.z = pack_bf2(o[4], o[5]);
            pk.w = pack_bf2(o[6], o[7]);
            *(uint4*)&hbout[(size_t)row * HBW + ct * 4] = pk;
        }
    }
}

// ---------------------------------------------------------------- pooling ---
__global__ __launch_bounds__(256) void count_nodes(const int* __restrict__ gid,
                                                   float* __restrict__ cnt) {
    int t = blockIdx.x * 256 + threadIdx.x;
    if (t < NN) atomicAdd(&cnt[gid[t]], 1.0f);
}

__global__ __launch_bounds__(256) void pool_sum_bf(const unsigned* __restrict__ hb,
                                                   const int* __restrict__ gid,
                                                   float* __restrict__ hg) {
    int tid = threadIdx.x;
    int c = tid & 63;                  // uint column (2 features)
    int grp = tid >> 6;                // 4 groups x 16 nodes
    int n0 = blockIdx.x * 64 + grp * 16;
    float ax = 0.f, ay = 0.f;
    int gcur = -1;
    for (int i = 0; i < 16; ++i) {
        int n = n0 + i;
        if (n >= NN) break;
        int g = gid[n];
        if (g != gcur) {
            if (gcur >= 0) {
                atomicAdd(&hg[gcur * DHID + 2 * c], ax);
                atomicAdd(&hg[gcur * DHID + 2 * c + 1], ay);
            }
            gcur = g;
            ax = ay = 0.f;
        }
        unsigned v = hb[(size_t)n * HBW + c];
        ax += bflo(v); ay += bfhi(v);
    }
    if (gcur >= 0) {
        atomicAdd(&hg[gcur * DHID + 2 * c], ax);
        atomicAdd(&hg[gcur * DHID + 2 * c + 1], ay);
    }
}

// ------------------------------------------------------------- classifier ---
__global__ __launch_bounds__(256) void classifier_k(const float* __restrict__ hg,
                                                    const float* __restrict__ cnt,
                                                    const float* __restrict__ Wc,
                                                    const float* __restrict__ bc,
                                                    float* __restrict__ out) {
    int t = blockIdx.x * 256 + threadIdx.x;
    if (t >= GG * NCLS) return;
    int g = t / NCLS;
    int c = t - g * NCLS;
    float inv = 1.0f / fmaxf(cnt[g], 1.0f);
    float acc = 0.f;
    #pragma unroll 4
    for (int k = 0; k < DHID; ++k)
        acc = fmaf(hg[g * DHID + k], Wc[k * NCLS + c], acc);
    out[t] = acc * inv + bc[c];
}

// ---------------------------------------------------------------- launch ----
extern "C" void kernel_launch(void* const* d_in, const int* in_sizes, int n_in,
                              void* d_out, int out_size, void* d_ws, size_t ws_size,
                              hipStream_t stream) {
    const float* features = (const float*)d_in[0];
    const int*   edges    = (const int*)d_in[1];
    const int*   gid      = (const int*)d_in[2];
    const float* W0       = (const float*)d_in[3];
    const float* b0       = (const float*)d_in[4];
    const float* Wl       = (const float*)d_in[5];
    const float* bl       = (const float*)d_in[6];
    const float* Wc       = (const float*)d_in[7];
    const float* bc       = (const float*)d_in[8];
    float* out = (float*)d_out;

    // ---- workspace carve-up ----
    int* iw = (int*)d_ws;
    size_t off = 0;
    int* cnt_out = iw + off; off += RN;
    int* cnt_in  = iw + off; off += RN;
    int* row_ptr = iw + off; off += RN + 1;
    int* cursor  = iw + off; off += RN;
    int* partial = iw + off; off += 512;
    int* order   = iw + off; off += 2048;
    off = (off + 3) & ~(size_t)3;            // 16B align
    int2* ew     = (int2*)(iw + off); off += (size_t)2 * RR * NE;
    float* so    = (float*)(iw + off); off += RN;
    float* si    = (float*)(iw + off); off += RN;
    float* hg    = (float*)(iw + off); off += (size_t)GG * DHID;
    float* cntg  = (float*)(iw + off); off += GG;
    off = (off + 3) & ~(size_t)3;
    unsigned* hb0 = (unsigned*)(iw + off); off += (size_t)NN * HBW;
    unsigned* hbA = (unsigned*)(iw + off); off += (size_t)NN * HBW;
    unsigned* hbB = (unsigned*)(iw + off); off += (size_t)NN * HBW;
    if (ws_size < off * sizeof(int)) return;

    // ---- degrees, scales, CSR (edges constant -> rebuild each call) ----
    hipMemsetAsync(cnt_out, 0, (size_t)2 * RN * sizeof(int), stream);
    degree_count<<<(RR * NE + 255) / 256, 256, 0, stream>>>(edges, cnt_out, cnt_in);
    deg_to_scale<<<(RN + 255) / 256, 256, 0, stream>>>(cnt_out, cnt_in, so, si);
    scan_partial<<<NBLK, 256, 0, stream>>>(cnt_in, partial);
    scan_block<<<1, 512, 0, stream>>>(partial);
    scan_write<<<NBLK, 256, 0, stream>>>(cnt_in, partial, row_ptr, cursor);
    fill_csr<<<(RR * NE + 255) / 256, 256, 0, stream>>>(edges, so, si, cursor, ew);
    tile_sort<<<1, 1024, 0, stream>>>(row_ptr, order);

    // ---- features -> bf16 ----
    f32_to_bf16<<<(NN * DHID / 4 + 255) / 256, 256, 0, stream>>>(features, hb0);

    // ---- 3 fused layers (bf16 h storage) ----
    const unsigned* hin[3]   = {hb0, hbA, hbB};
    unsigned*       hout_[3] = {hbA, hbB, hbA};
    for (int l = 0; l < 3; ++l) {
        const float* Wp = (l == 0) ? W0 : Wl + (size_t)(l - 1) * RR * DHID * DHID;
        const float* bp = (l == 0) ? b0 : bl + (size_t)(l - 1) * RR * DHID;
        layer_kernel<<<NTILE, 256, 0, stream>>>(
            hin[l], row_ptr, ew, order, Wp, bp, hout_[l]);
    }

    // ---- pooling + classifier ----
    hipMemsetAsync(hg, 0, ((size_t)GG * DHID + GG) * sizeof(float), stream);
    count_nodes<<<(NN + 255) / 256, 256, 0, stream>>>(gid, cntg);
    pool_sum_bf<<<(NN + 63) / 64, 256, 0, stream>>>(hbA, gid, hg);
    classifier_k<<<(GG * NCLS + 255) / 256, 256, 0, stream>>>(hg, cntg, Wc, bc, out);
}

// Round 8
// 1576.271 us; speedup vs baseline: 1.4436x; 1.4436x over previous
//
#include <hip/hip_runtime.h>

#define NN 100000      // nodes
#define NE 1000000     // edges per relation
#define RR 4           // relations
#define GG 256         // graphs
#define DHID 128       // feature width (DIN == DH == 128)
#define NCLS 10        // classes
#define RN (RR * NN)   // virtual segments (r, dst)
#define NBLK ((RN + 1023) / 1024)
#define HBW 64         // packed bf16 row width in uints (128 bf16)
#define AST 136        // LDS A-tile row stride in shorts (272B, 16B-aligned)

typedef __attribute__((ext_vector_type(8))) short short8;
typedef __attribute__((ext_vector_type(4))) float f32x4;

// ---- bf16 helpers (packed 2 per uint; low ushort = even col) ----
__device__ __forceinline__ float bflo(unsigned v) { return __int_as_float((int)(v << 16)); }
__device__ __forceinline__ float bfhi(unsigned v) { return __int_as_float((int)(v & 0xffff0000u)); }
__device__ __forceinline__ unsigned pack_bf2(float a, float b) {
    unsigned ua = __float_as_uint(a), ub = __float_as_uint(b);
    ua = (ua + 0x7fffu + ((ua >> 16) & 1u)) >> 16;     // round-to-nearest-even
    ub = (ub + 0x7fffu + ((ub >> 16) & 1u)) >> 16;
    return ua | (ub << 16);
}

// ---------------------------------------------------------------- degrees ---
__global__ __launch_bounds__(256) void degree_count(const int* __restrict__ edges,
                                                    int* __restrict__ cnt_out,
                                                    int* __restrict__ cnt_in) {
    int t = blockIdx.x * 256 + threadIdx.x;
    if (t >= RR * NE) return;
    int r = t / NE;
    int e = t - r * NE;
    const int* base = edges + (size_t)r * 2 * NE;
    atomicAdd(&cnt_out[r * NN + base[e]], 1);
    atomicAdd(&cnt_in[r * NN + base[NE + e]], 1);
}

__global__ __launch_bounds__(256) void deg_to_scale(const int* __restrict__ cnt_out,
                                                    const int* __restrict__ cnt_in,
                                                    float* __restrict__ so,
                                                    float* __restrict__ si) {
    int t = blockIdx.x * 256 + threadIdx.x;
    if (t >= RN) return;
    int co = cnt_out[t], ci = cnt_in[t];
    so[t] = rsqrtf((float)(co < 1 ? 1 : co));
    si[t] = rsqrtf((float)(ci < 1 ? 1 : ci));
}

// ------------------------------------------------------------- CSR build ----
__global__ __launch_bounds__(256) void scan_partial(const int* __restrict__ cnt,
                                                    int* __restrict__ partial) {
    __shared__ int sdat[256];
    int t = threadIdx.x;
    int base = blockIdx.x * 1024 + t * 4;
    int s = 0;
    #pragma unroll
    for (int i = 0; i < 4; ++i)
        if (base + i < RN) s += cnt[base + i];
    sdat[t] = s;
    __syncthreads();
    for (int off = 128; off > 0; off >>= 1) {
        if (t < off) sdat[t] += sdat[t + off];
        __syncthreads();
    }
    if (t == 0) partial[blockIdx.x] = sdat[0];
}

__global__ __launch_bounds__(512) void scan_block(int* __restrict__ partial) {
    __shared__ int s[512];
    int t = threadIdx.x;
    s[t] = (t < NBLK) ? partial[t] : 0;
    __syncthreads();
    for (int off = 1; off < 512; off <<= 1) {
        int v = (t >= off) ? s[t - off] : 0;
        __syncthreads();
        s[t] += v;
        __syncthreads();
    }
    if (t < NBLK) partial[t] = (t == 0) ? 0 : s[t - 1];
}

__global__ __launch_bounds__(256) void scan_write(const int* __restrict__ cnt,
                                                  const int* __restrict__ partial,
                                                  int* __restrict__ row_ptr,
                                                  int* __restrict__ cursor) {
    __shared__ int ssum[256];
    int t = threadIdx.x;
    int base = blockIdx.x * 1024 + t * 4;
    int c[4];
    #pragma unroll
    for (int i = 0; i < 4; ++i)
        c[i] = (base + i < RN) ? cnt[base + i] : 0;
    ssum[t] = c[0] + c[1] + c[2] + c[3];
    __syncthreads();
    for (int off = 1; off < 256; off <<= 1) {
        int v = (t >= off) ? ssum[t - off] : 0;
        __syncthreads();
        ssum[t] += v;
        __syncthreads();
    }
    int e = partial[blockIdx.x] + (t == 0 ? 0 : ssum[t - 1]);
    #pragma unroll
    for (int i = 0; i < 4; ++i) {
        if (base + i < RN) { row_ptr[base + i] = e; cursor[base + i] = e; e += c[i]; }
    }
    if (blockIdx.x == 0 && t == 0) row_ptr[RN] = RR * NE;
}

// packed edge record: .x = src index, .y = float bits of so[src]*si[dst]
__global__ __launch_bounds__(256) void fill_csr(const int* __restrict__ edges,
                                                const float* __restrict__ so,
                                                const float* __restrict__ si,
                                                int* __restrict__ cursor,
                                                int2* __restrict__ ew) {
    int t = blockIdx.x * 256 + threadIdx.x;
    if (t >= RR * NE) return;
    int r = t / NE;
    int e = t - r * NE;
    const int* eb = edges + (size_t)r * 2 * NE;
    int s = eb[e];
    int d = eb[NE + e];
    int rb = r * NN;
    float w = so[rb + s] * si[rb + d];
    int pos = atomicAdd(&cursor[rb + d], 1);
    ew[pos] = make_int2(s, __float_as_int(w));
}

// ------------------------------------------------------------- f32 -> bf16 --
__global__ __launch_bounds__(256) void f32_to_bf16(const float* __restrict__ in,
                                                   unsigned* __restrict__ out) {
    int t = blockIdx.x * 256 + threadIdx.x;
    if (t >= NN * DHID / 4) return;
    float4 v = ((const float4*)in)[t];
    uint2 o;
    o.x = pack_bf2(v.x, v.y);
    o.y = pack_bf2(v.z, v.w);
    ((uint2*)out)[t] = o;
}

// ------------------------------------------------------------- W prep -------
// Wb[(m*8+c)*4+ks][lane] = 8 bf16: W_m[k][col], k = ks*32 + (lane>>4)*8 + e,
// col = c*16 + (lane&15). Contiguous-k frag map, consistent A/B (m91/m92).
__global__ __launch_bounds__(256) void w_prep(const float* __restrict__ W0,
                                              const float* __restrict__ Wl,
                                              uint4* __restrict__ Wb) {
    int t = blockIdx.x * 256 + threadIdx.x;
    if (t >= 12 * 8 * 4 * 64) return;
    int l  = t & 63;
    int ks = (t >> 6) & 3;
    int c  = (t >> 8) & 7;
    int m  = t >> 11;            // 0..11 = layer*4 + r
    const float* Ws = (m < 4) ? (W0 + (size_t)m * DHID * DHID)
                              : (Wl + (size_t)(m - 4) * DHID * DHID);
    int col = c * 16 + (l & 15);
    int k0  = ks * 32 + (l >> 4) * 8;
    unsigned sh[4];
    #pragma unroll
    for (int p = 0; p < 4; ++p) {
        float e0 = Ws[(size_t)(k0 + 2 * p) * DHID + col];
        float e1 = Ws[(size_t)(k0 + 2 * p + 1) * DHID + col];
        sh[p] = pack_bf2(e0, e1);
    }
    Wb[t] = make_uint4(sh[0], sh[1], sh[2], sh[3]);
}

__global__ __launch_bounds__(256) void bsum_prep(const float* __restrict__ b0,
                                                 const float* __restrict__ bl,
                                                 float* __restrict__ bsum) {
    int t = blockIdx.x * 256 + threadIdx.x;
    if (t >= 3 * DHID) return;
    int layer = t >> 7;
    int col = t & 127;
    const float* bp = (layer == 0) ? b0 : bl + (size_t)(layer - 1) * RR * DHID;
    bsum[t] = bp[col] + bp[DHID + col] + bp[2 * DHID + col] + bp[3 * DHID + col];
}

// ------------------------------------------------------------- layer --------
// Barrier-free layer: wave w owns dst rows w*16..w*16+15 (its private 16x128
// A-tile in LDS). Per relation: gather (round-6 scheme: scalar edge stream,
// 8 independent 256B row loads in flight) -> ds_write; then 4 ds_read_b128
// A-frags + 32 MFMA (16x16x32 bf16) with pre-swizzled Wb B-frags, accumulated
// over all 4 relations in 8 f32x4. Epilogue: +bsum, ReLU, shfl-pair pack,
// uint store. No __syncthreads anywhere.
__global__ __launch_bounds__(256, 4) void layer_kernel(
    const unsigned* __restrict__ hb, const int* __restrict__ row_ptr,
    const int2* __restrict__ ew, const short8* __restrict__ Wb,
    const float* __restrict__ bsum, unsigned* __restrict__ hbout) {
    __shared__ unsigned short As[4][16 * AST];
    const int tid  = threadIdx.x;
    const int wave = tid >> 6;
    const int lane = tid & 63;
    const int rowbase = blockIdx.x * 64 + wave * 16;

    f32x4 acc[8];
    #pragma unroll
    for (int c = 0; c < 8; ++c) acc[c] = (f32x4){0.f, 0.f, 0.f, 0.f};

    for (int r = 0; r < RR; ++r) {
        const int rbase = r * NN;

        // ---- gather: 16 private rows; scalar edge stream, 8-deep MLP ----
        for (int rr = 0; rr < 16; ++rr) {
            int d = rowbase + rr;
            float ax = 0.f, ay = 0.f;
            if (d < NN) {
                int j   = __builtin_amdgcn_readfirstlane(row_ptr[rbase + d]);
                int end = __builtin_amdgcn_readfirstlane(row_ptr[rbase + d + 1]);
                for (; j + 8 <= end; j += 8) {
                    int2 p0 = ew[j],     p1 = ew[j + 1], p2 = ew[j + 2], p3 = ew[j + 3];
                    int2 p4 = ew[j + 4], p5 = ew[j + 5], p6 = ew[j + 6], p7 = ew[j + 7];
                    unsigned u0 = hb[(size_t)p0.x * HBW + lane];
                    unsigned u1 = hb[(size_t)p1.x * HBW + lane];
                    unsigned u2 = hb[(size_t)p2.x * HBW + lane];
                    unsigned u3 = hb[(size_t)p3.x * HBW + lane];
                    unsigned u4 = hb[(size_t)p4.x * HBW + lane];
                    unsigned u5 = hb[(size_t)p5.x * HBW + lane];
                    unsigned u6 = hb[(size_t)p6.x * HBW + lane];
                    unsigned u7 = hb[(size_t)p7.x * HBW + lane];
                    float w0 = __int_as_float(p0.y), w1 = __int_as_float(p1.y);
                    float w2 = __int_as_float(p2.y), w3 = __int_as_float(p3.y);
                    float w4 = __int_as_float(p4.y), w5 = __int_as_float(p5.y);
                    float w6 = __int_as_float(p6.y), w7 = __int_as_float(p7.y);
                    ax = fmaf(w0, bflo(u0), ax); ay = fmaf(w0, bfhi(u0), ay);
                    ax = fmaf(w1, bflo(u1), ax); ay = fmaf(w1, bfhi(u1), ay);
                    ax = fmaf(w2, bflo(u2), ax); ay = fmaf(w2, bfhi(u2), ay);
                    ax = fmaf(w3, bflo(u3), ax); ay = fmaf(w3, bfhi(u3), ay);
                    ax = fmaf(w4, bflo(u4), ax); ay = fmaf(w4, bfhi(u4), ay);
                    ax = fmaf(w5, bflo(u5), ax); ay = fmaf(w5, bfhi(u5), ay);
                    ax = fmaf(w6, bflo(u6), ax); ay = fmaf(w6, bfhi(u6), ay);
                    ax = fmaf(w7, bflo(u7), ax); ay = fmaf(w7, bfhi(u7), ay);
                }
                if (j + 4 <= end) {
                    int2 p0 = ew[j], p1 = ew[j + 1], p2 = ew[j + 2], p3 = ew[j + 3];
                    unsigned u0 = hb[(size_t)p0.x * HBW + lane];
                    unsigned u1 = hb[(size_t)p1.x * HBW + lane];
                    unsigned u2 = hb[(size_t)p2.x * HBW + lane];
                    unsigned u3 = hb[(size_t)p3.x * HBW + lane];
                    float w0 = __int_as_float(p0.y), w1 = __int_as_float(p1.y);
                    float w2 = __int_as_float(p2.y), w3 = __int_as_float(p3.y);
                    ax = fmaf(w0, bflo(u0), ax); ay = fmaf(w0, bfhi(u0), ay);
                    ax = fmaf(w1, bflo(u1), ax); ay = fmaf(w1, bfhi(u1), ay);
                    ax = fmaf(w2, bflo(u2), ax); ay = fmaf(w2, bfhi(u2), ay);
                    ax = fmaf(w3, bflo(u3), ax); ay = fmaf(w3, bfhi(u3), ay);
                    j += 4;
                }
                for (; j < end; ++j) {
                    int2 p = ew[j];
                    unsigned u = hb[(size_t)p.x * HBW + lane];
                    float w = __int_as_float(p.y);
                    ax = fmaf(w, bflo(u), ax); ay = fmaf(w, bfhi(u), ay);
                }
            }
            *(unsigned*)&As[wave][rr * AST + 2 * lane] = pack_bf2(ax, ay);
        }

        // ---- MFMA GEMM: acc[c] += A(16x128) @ W_r[:, c*16..+15] ----
        const short8* wb = Wb + (size_t)r * 2048;       // 8c * 4ks * 64 lanes
        short8 af[4];
        #pragma unroll
        for (int s = 0; s < 4; ++s)
            af[s] = *(const short8*)&As[wave][(lane & 15) * AST + s * 32 + (lane >> 4) * 8];
        #pragma unroll
        for (int c = 0; c < 8; ++c) {
            #pragma unroll
            for (int s = 0; s < 4; ++s) {
                short8 bf = wb[(c * 4 + s) * 64 + lane];
                acc[c] = __builtin_amdgcn_mfma_f32_16x16x32_bf16(af[s], bf, acc[c], 0, 0, 0);
            }
        }
    }

    // ---- epilogue: + bsum, ReLU, pair-pack via shfl, store ----
    const int colbase = lane & 15;                      // output col within tile
    #pragma unroll
    for (int c = 0; c < 8; ++c) {
        float bs = bsum[c * 16 + colbase];
        #pragma unroll
        for (int e = 0; e < 4; ++e) {
            float o = fmaxf(acc[c][e] + bs, 0.f);
            float po = __shfl_xor(o, 1);                // partner col (^1)
            int row = rowbase + (lane >> 4) * 4 + e;    // C/D map (m89)
            if (!(lane & 1) && row < NN)
                hbout[(size_t)row * HBW + c * 8 + (colbase >> 1)] = pack_bf2(o, po);
        }
    }
}

// ---------------------------------------------------------------- pooling ---
__global__ __launch_bounds__(256) void count_nodes(const int* __restrict__ gid,
                                                   float* __restrict__ cnt) {
    int t = blockIdx.x * 256 + threadIdx.x;
    if (t < NN) atomicAdd(&cnt[gid[t]], 1.0f);
}

__global__ __launch_bounds__(256) void pool_sum_bf(const unsigned* __restrict__ hb,
                                                   const int* __restrict__ gid,
                                                   float* __restrict__ hg) {
    int tid = threadIdx.x;
    int c = tid & 63;                  // uint column (2 features)
    int grp = tid >> 6;                // 4 groups x 16 nodes
    int n0 = blockIdx.x * 64 + grp * 16;
    float ax = 0.f, ay = 0.f;
    int gcur = -1;
    for (int i = 0; i < 16; ++i) {
        int n = n0 + i;
        if (n >= NN) break;
        int g = gid[n];
        if (g != gcur) {
            if (gcur >= 0) {
                atomicAdd(&hg[gcur * DHID + 2 * c], ax);
                atomicAdd(&hg[gcur * DHID + 2 * c + 1], ay);
            }
            gcur = g;
            ax = ay = 0.f;
        }
        unsigned v = hb[(size_t)n * HBW + c];
        ax += bflo(v); ay += bfhi(v);
    }
    if (gcur >= 0) {
        atomicAdd(&hg[gcur * DHID + 2 * c], ax);
        atomicAdd(&hg[gcur * DHID + 2 * c + 1], ay);
    }
}

// ------------------------------------------------------------- classifier ---
__global__ __launch_bounds__(256) void classifier_k(const float* __restrict__ hg,
                                                    const float* __restrict__ cnt,
                                                    const float* __restrict__ Wc,
                                                    const float* __restrict__ bc,
                                                    float* __restrict__ out) {
    int t = blockIdx.x * 256 + threadIdx.x;
    if (t >= GG * NCLS) return;
    int g = t / NCLS;
    int c = t - g * NCLS;
    float inv = 1.0f / fmaxf(cnt[g], 1.0f);
    float acc = 0.f;
    #pragma unroll 4
    for (int k = 0; k < DHID; ++k)
        acc = fmaf(hg[g * DHID + k], Wc[k * NCLS + c], acc);
    out[t] = acc * inv + bc[c];
}

// ---------------------------------------------------------------- launch ----
extern "C" void kernel_launch(void* const* d_in, const int* in_sizes, int n_in,
                              void* d_out, int out_size, void* d_ws, size_t ws_size,
                              hipStream_t stream) {
    const float* features = (const float*)d_in[0];
    const int*   edges    = (const int*)d_in[1];
    const int*   gid      = (const int*)d_in[2];
    const float* W0       = (const float*)d_in[3];
    const float* b0       = (const float*)d_in[4];
    const float* Wl       = (const float*)d_in[5];
    const float* bl       = (const float*)d_in[6];
    const float* Wc       = (const float*)d_in[7];
    const float* bc       = (const float*)d_in[8];
    float* out = (float*)d_out;

    // ---- workspace carve-up ----
    int* iw = (int*)d_ws;
    size_t off = 0;
    int* cnt_out = iw + off; off += RN;
    int* cnt_in  = iw + off; off += RN;
    int* row_ptr = iw + off; off += RN + 1;
    int* cursor  = iw + off; off += RN;
    int* partial = iw + off; off += 512;
    off = (off + 3) & ~(size_t)3;            // 16B align
    int2* ew     = (int2*)(iw + off); off += (size_t)2 * RR * NE;
    uint4* Wb    = (uint4*)(iw + off); off += (size_t)12 * 8 * 4 * 64 * 4;
    float* bsum  = (float*)(iw + off); off += 3 * DHID;
    float* so    = (float*)(iw + off); off += RN;
    float* si    = (float*)(iw + off); off += RN;
    float* hg    = (float*)(iw + off); off += (size_t)GG * DHID;
    float* cntg  = (float*)(iw + off); off += GG;
    off = (off + 3) & ~(size_t)3;
    unsigned* hb0 = (unsigned*)(iw + off); off += (size_t)NN * HBW;
    unsigned* hbA = (unsigned*)(iw + off); off += (size_t)NN * HBW;
    unsigned* hbB = (unsigned*)(iw + off); off += (size_t)NN * HBW;
    if (ws_size < off * sizeof(int)) return;

    // ---- degrees, scales, CSR (edges constant -> rebuild each call) ----
    hipMemsetAsync(cnt_out, 0, (size_t)2 * RN * sizeof(int), stream);
    degree_count<<<(RR * NE + 255) / 256, 256, 0, stream>>>(edges, cnt_out, cnt_in);
    deg_to_scale<<<(RN + 255) / 256, 256, 0, stream>>>(cnt_out, cnt_in, so, si);
    scan_partial<<<NBLK, 256, 0, stream>>>(cnt_in, partial);
    scan_block<<<1, 512, 0, stream>>>(partial);
    scan_write<<<NBLK, 256, 0, stream>>>(cnt_in, partial, row_ptr, cursor);
    fill_csr<<<(RR * NE + 255) / 256, 256, 0, stream>>>(edges, so, si, cursor, ew);

    // ---- weight/bias prep + features -> bf16 ----
    w_prep<<<(12 * 8 * 4 * 64 + 255) / 256, 256, 0, stream>>>(W0, Wl, Wb);
    bsum_prep<<<2, 256, 0, stream>>>(b0, bl, bsum);
    f32_to_bf16<<<(NN * DHID / 4 + 255) / 256, 256, 0, stream>>>(features, hb0);

    // ---- 3 fused layers (bf16 h storage, MFMA GEMM, barrier-free) ----
    const unsigned* hin[3]   = {hb0, hbA, hbB};
    unsigned*       hout_[3] = {hbA, hbB, hbA};
    for (int l = 0; l < 3; ++l) {
        layer_kernel<<<(NN + 63) / 64, 256, 0, stream>>>(
            hin[l], row_ptr, ew,
            (const short8*)Wb + (size_t)l * 4 * 2048, bsum + (size_t)l * DHID,
            hout_[l]);
    }

    // ---- pooling + classifier ----
    hipMemsetAsync(hg, 0, ((size_t)GG * DHID + GG) * sizeof(float), stream);
    count_nodes<<<(NN + 255) / 256, 256, 0, stream>>>(gid, cntg);
    pool_sum_bf<<<(NN + 63) / 64, 256, 0, stream>>>(hbA, gid, hg);
    classifier_k<<<(GG * NCLS + 255) / 256, 256, 0, stream>>>(hg, cntg, Wc, bc, out);
}